// Round 22
// baseline (191.594 us; speedup 1.0000x reference)
//
#include <hip/hip_runtime.h>
#include <hip/hip_fp16.h>
#include <math.h>

#define N_NODES 10000
#define N_PAD 10240    // deg array padded for int4 scan reads
#define B_BATCH 4
#define F_IN_C 128
#define HID_C 64
#define E_EDGES 160000
#define E_TOT (E_EDGES + N_NODES)
#define E_OCT 240000   // E_TOT + 7*N_NODES upper bound (oct-padded)
#define NEG_SLOPE 0.2f
#define LOG2E 1.44269504f
#define SN (N_NODES + 8)   // alsrc/aldst node stride per batch (row N = dummy, -1e30)
#define SH (N_NODES + 8)   // h2 rows per batch (row N = dummy, zeros)

typedef _Float16 half8 __attribute__((ext_vector_type(8)));
typedef float f32x4 __attribute__((ext_vector_type(4)));

// ---------------- deg zero ----------------

__global__ void k_zero(int* __restrict__ deg) {
    deg[blockIdx.x * 256 + threadIdx.x] = 0;   // 40 blocks x 256 == N_PAD exactly
}

// ---------------- Wt_ext: fp16 col-major [272][K]; 256+hd=W@a_src, 260+hd=W@a_dst --------------
// al columns pre-scaled by log2(e) (leaky is positively homogeneous -> raw v_exp_f32 in k_agg).

__device__ void wext_body(const float* __restrict__ W, const float* __restrict__ asrc,
                          const float* __restrict__ adst, __half* __restrict__ Wt,
                          int tid, int K) {
    int nc = tid / K, k = tid % K;
    float v;
    if (nc < 256) {
        v = W[k * 256 + nc];
    } else if (nc < 260) {
        int hd = nc - 256; v = 0.f;
        for (int c = 0; c < 64; c++) v += W[k * 256 + hd * 64 + c] * asrc[hd * 64 + c];
        v *= LOG2E;
    } else if (nc < 264) {
        int hd = nc - 260; v = 0.f;
        for (int c = 0; c < 64; c++) v += W[k * 256 + hd * 64 + c] * adst[hd * 64 + c];
        v *= LOG2E;
    } else {
        v = 0.f;
    }
    Wt[(size_t)nc * K + k] = __float2half(v);
}

// ---------------- Mega-setup: wext1 | wext2 | csr sentinel-fill | dummy rows | deg_count --------

__global__ void k_setup(const float* __restrict__ W1, const float* __restrict__ as1,
                        const float* __restrict__ ad1, const float* __restrict__ W2,
                        const float* __restrict__ as2, const float* __restrict__ ad2,
                        __half* __restrict__ Wt1, __half* __restrict__ Wt2,
                        int* __restrict__ csr_b, __half* __restrict__ h2,
                        float* __restrict__ alsrc, int* __restrict__ deg,
                        const int* __restrict__ ei) {
    int blk = blockIdx.x, t = threadIdx.x;
    if (blk < 136) {
        wext_body(W1, as1, ad1, Wt1, blk * 256 + t, F_IN_C);
    } else if (blk < 204) {
        wext_body(W2, as2, ad2, Wt2, (blk - 136) * 256 + t, HID_C);
    } else if (blk < 1142) {
        int i = (blk - 204) * 256 + t;
        if (i < E_OCT) csr_b[i] = N_NODES << 9;   // dummy sentinel
    } else if (blk == 1142) {
        for (int i = t; i < 4 * 256; i += 256) {   // dummy h2 rows = 0
            int b = i >> 8, c = i & 255;
            h2[((size_t)b * SH + N_NODES) * 256 + c] = __float2half(0.f);
        }
        if (t < 16) {                              // dummy alsrc = -1e30
            int b = t >> 2, q = t & 3;
            alsrc[((size_t)b * SN + N_NODES) * 4 + q] = -1e30f;
        }
    } else {
        int e = (blk - 1143) * 256 + t;
        if (e < E_EDGES) atomicAdd(&deg[ei[E_EDGES + e]], 1);
    }
}

// ---------------- MFMA GEMM body: h = x@W (fp16 in, f32 accum, node-major fp16 out) ------------

template <int K, typename XT>
__device__ void gemm_body(const XT* __restrict__ x, const __half* __restrict__ Wt,
                          __half* __restrict__ h2, float* __restrict__ alsrc,
                          float* __restrict__ aldst, int b, int tile) {
    int t = threadIdx.x;
    int w = t >> 6, lane = t & 63;
    int node0 = tile * 16;
    int col = lane & 15, kblk = lane >> 4;

    const XT* xr = x + ((size_t)b * N_NODES + node0 + col) * K + kblk * 8;

    f32x4 acc0 = {0.f, 0.f, 0.f, 0.f};
    f32x4 acc1 = {0.f, 0.f, 0.f, 0.f};
    f32x4 acc2 = {0.f, 0.f, 0.f, 0.f};
    f32x4 acc3 = {0.f, 0.f, 0.f, 0.f};
    f32x4 accal = {0.f, 0.f, 0.f, 0.f};

#pragma unroll
    for (int k0 = 0; k0 < K; k0 += 32) {
        half8 a;
        if constexpr (sizeof(XT) == 4) {
            float4 xa = *(const float4*)(xr + k0);
            float4 xc = *(const float4*)(xr + k0 + 4);
            a[0] = (_Float16)xa.x; a[1] = (_Float16)xa.y; a[2] = (_Float16)xa.z; a[3] = (_Float16)xa.w;
            a[4] = (_Float16)xc.x; a[5] = (_Float16)xc.y; a[6] = (_Float16)xc.z; a[7] = (_Float16)xc.w;
        } else {
            a = *(const half8*)(xr + k0);
        }
        const __half* wtk = Wt + kblk * 8 + k0;
        half8 b0 = *(const half8*)(wtk + (size_t)((w * 4 + 0) * 16 + col) * K);
        half8 b1 = *(const half8*)(wtk + (size_t)((w * 4 + 1) * 16 + col) * K);
        half8 b2 = *(const half8*)(wtk + (size_t)((w * 4 + 2) * 16 + col) * K);
        half8 b3 = *(const half8*)(wtk + (size_t)((w * 4 + 3) * 16 + col) * K);
        acc0 = __builtin_amdgcn_mfma_f32_16x16x32_f16(a, b0, acc0, 0, 0, 0);
        acc1 = __builtin_amdgcn_mfma_f32_16x16x32_f16(a, b1, acc1, 0, 0, 0);
        acc2 = __builtin_amdgcn_mfma_f32_16x16x32_f16(a, b2, acc2, 0, 0, 0);
        acc3 = __builtin_amdgcn_mfma_f32_16x16x32_f16(a, b3, acc3, 0, 0, 0);
        if (w == 0) {
            half8 bal = *(const half8*)(wtk + (size_t)(256 + col) * K);
            accal = __builtin_amdgcn_mfma_f32_16x16x32_f16(a, bal, accal, 0, 0, 0);
        }
    }

    {   // node-major store: h2[(b*SH + node)*256 + w*64 + nt*16 + col]
        __half* dst = h2 + ((size_t)b * SH + node0 + kblk * 4) * 256 + w * 64 + col;
#pragma unroll
        for (int r = 0; r < 4; r++) dst[(size_t)r * 256 + 0 * 16] = __float2half(acc0[r]);
#pragma unroll
        for (int r = 0; r < 4; r++) dst[(size_t)r * 256 + 1 * 16] = __float2half(acc1[r]);
#pragma unroll
        for (int r = 0; r < 4; r++) dst[(size_t)r * 256 + 2 * 16] = __float2half(acc2[r]);
#pragma unroll
        for (int r = 0; r < 4; r++) dst[(size_t)r * 256 + 3 * 16] = __float2half(acc3[r]);
    }
    if (w == 0 && col < 8) {
        int node = node0 + kblk * 4;
        if (col < 4) {
            float* d = alsrc + ((size_t)b * SN + node) * 4 + col;
#pragma unroll
            for (int r = 0; r < 4; r++) d[r * 4] = accal[r];
        } else {
            float* d = aldst + ((size_t)b * SN + node) * 4 + (col - 4);
#pragma unroll
            for (int r = 0; r < 4; r++) d[r * 4] = accal[r];
        }
    }
}

// ---------------- Scan (256 threads; int4-vectorized loads, fully pipelined) ----------------

__device__ void scan_body(const int* __restrict__ deg, int* __restrict__ offs,
                          int* __restrict__ cursor) {
    __shared__ int lds[256];
    int t = threadIdx.x;
    int i0 = t * 40;
    int v[40];
#pragma unroll
    for (int q = 0; q < 10; q++) {
        int4 d4 = *(const int4*)(deg + i0 + q * 4);
        v[q * 4 + 0] = (d4.x + 8) & ~7;   // (deg + 1 self-loop + 7) & ~7
        v[q * 4 + 1] = (d4.y + 8) & ~7;
        v[q * 4 + 2] = (d4.z + 8) & ~7;
        v[q * 4 + 3] = (d4.w + 8) & ~7;
    }
    int tot = 0;
#pragma unroll
    for (int j = 0; j < 40; j++) tot += v[j];
    lds[t] = tot;
    __syncthreads();
    for (int ofs = 1; ofs < 256; ofs <<= 1) {
        int w = (t >= ofs) ? lds[t - ofs] : 0;
        __syncthreads();
        lds[t] += w;
        __syncthreads();
    }
    int run = lds[t] - tot;
#pragma unroll
    for (int j = 0; j < 40; j++) {
        int i = i0 + j;
        if (i < N_NODES) {
            cursor[i] = run;
            offs[i + 1] = run + v[j];
        }
        run += v[j];
    }
    if (t == 0) offs[0] = 0;
}

// ---------------- Fused dispatch: scan (block 0) || gemm1 (blocks 1..2500) ----------------

__launch_bounds__(256)
__global__ void k_gemm1_scan(const float* __restrict__ x, const __half* __restrict__ Wt,
                             __half* __restrict__ h2, float* __restrict__ alsrc,
                             float* __restrict__ aldst, const int* __restrict__ deg,
                             int* __restrict__ offs, int* __restrict__ cursor) {
    int bid = blockIdx.x;
    if (bid == 0) { scan_body(deg, offs, cursor); return; }
    gemm_body<F_IN_C, float>(x, Wt, h2, alsrc, aldst, (bid - 1) / 625, (bid - 1) % 625);
}

__launch_bounds__(256)
__global__ void k_gemm2(const __half* __restrict__ x2, const __half* __restrict__ Wt,
                        __half* __restrict__ h2, float* __restrict__ alsrc,
                        float* __restrict__ aldst) {
    gemm_body<HID_C, __half>(x2, Wt, h2, alsrc, aldst, blockIdx.y, blockIdx.x);
}

// ---------------- Scatter: real edges overwrite sentinel fill ----------------

__global__ void k_scatter(const int* __restrict__ ei, int* __restrict__ cursor,
                          int* __restrict__ csr_b) {
    int e = blockIdx.x * 256 + threadIdx.x;
    if (e < E_TOT) {
        int s, d;
        if (e < E_EDGES) { s = ei[e]; d = ei[E_EDGES + e]; }
        else { s = d = e - E_EDGES; }
        int pos = atomicAdd(&cursor[d], 1);
        csr_b[pos] = s << 9;     // src * 512 bytes (node-major fp16 row)
    }
}

// ---------------- Edge-ordered alpha-source build: alse[b][hd][j] = alsrc[b][src(j)][hd] --------
// Converts k_agg's 8 scalar per-oct als gathers into 2 coalesced float4 loads.
// Sentinel edges (src = N) copy the -1e30 dummy -> e = 0 downstream.

__global__ void k_alse(const int* __restrict__ csr_b, const float* __restrict__ alsrc,
                       float* __restrict__ alse) {
    int j = blockIdx.x * 256 + threadIdx.x;
    if (j >= E_OCT) return;
    int b = blockIdx.y;
    int src4 = csr_b[j] >> 7;  // (src*512) -> src*4
    float4 a4 = *(const float4*)(alsrc + (size_t)b * SN * 4 + src4);
    size_t base = (size_t)b * 4 * E_OCT + j;
    alse[base] = a4.x;
    alse[base + E_OCT] = a4.y;
    alse[base + (size_t)2 * E_OCT] = a4.z;
    alse[base + (size_t)3 * E_OCT] = a4.w;
}

// ---------------- 4-head fused gather-aggregate, oct depth-2 pipeline, 12 VMEM/oct -------------
// r21 post-mortem: ~16 cyc/VMEM-instruction TA throughput x 18 VMEM/oct == measured duration.
// alse cuts per-oct VMEM 18 -> 12 (8 gathers + 2 idx + 2 alpha float4).

#define EDGE_FMA(av, g)                                                                   \
    {                                                                                     \
        float v_ = av + ad_h;                                                             \
        v_ = fmaxf(v_, NEG_SLOPE * v_);                                                   \
        float e_;                                                                         \
        asm("v_exp_f32 %0, %1" : "=v"(e_) : "v"(v_));                                     \
        asm("v_fma_mix_f32 %0, %1, %2, %0 op_sel:[0,0,0] op_sel_hi:[1,0,0]"               \
            : "+v"(acc.x) : "v"(g.x), "v"(e_));                                           \
        asm("v_fma_mix_f32 %0, %1, %2, %0 op_sel:[1,0,0] op_sel_hi:[1,0,0]"               \
            : "+v"(acc.y) : "v"(g.x), "v"(e_));                                           \
        asm("v_fma_mix_f32 %0, %1, %2, %0 op_sel:[0,0,0] op_sel_hi:[1,0,0]"               \
            : "+v"(acc.z) : "v"(g.y), "v"(e_));                                           \
        asm("v_fma_mix_f32 %0, %1, %2, %0 op_sel:[1,0,0] op_sel_hi:[1,0,0]"               \
            : "+v"(acc.w) : "v"(g.y), "v"(e_));                                           \
        sacc += e_;                                                                       \
    }

template <bool LAYER1>
__launch_bounds__(256)
__global__ void k_agg(const __half* __restrict__ h2, const float* __restrict__ alse,
                      const float* __restrict__ aldst, const int* __restrict__ offs,
                      const int* __restrict__ csr_b, const float* __restrict__ bias,
                      void* __restrict__ outv) {
    int t = threadIdx.x;
    int bid = blockIdx.x;
    int xcd = bid & 7;
    int b = xcd >> 1;
    int local = (bid >> 3) * 2 + (xcd & 1); // 0..2499
    int wv = t >> 6, lane = t & 63;
    int hd = lane >> 4, cl = lane & 15;
    int dst = local * 4 + wv;

    const char* hcb = (const char*)(h2 + (size_t)b * SH * 256);
    const float* aep = alse + (size_t)(b * 4 + hd) * E_OCT;
    float ad_h = aldst[((size_t)b * SN + dst) * 4 + hd];
    int s0 = offs[dst], s1 = offs[dst + 1];
    int laneoff = (hd << 7) | (cl << 3);    // head slice (128 B) + chan quad (8 B)

    float4 acc = make_float4(0.f, 0.f, 0.f, 0.f);
    float sacc = 0.f;
    // prologue: oct 0 fully staged (padded len >= 8)
    int4 cA = *(const int4*)(csr_b + s0);
    int4 cB = *(const int4*)(csr_b + s0 + 4);
    float4 pA = *(const float4*)(aep + s0);
    float4 pB = *(const float4*)(aep + s0 + 4);
    uint2 g0 = *(const uint2*)(hcb + (unsigned)(cA.x + laneoff));
    uint2 g1 = *(const uint2*)(hcb + (unsigned)(cA.y + laneoff));
    uint2 g2 = *(const uint2*)(hcb + (unsigned)(cA.z + laneoff));
    uint2 g3 = *(const uint2*)(hcb + (unsigned)(cA.w + laneoff));
    uint2 g4 = *(const uint2*)(hcb + (unsigned)(cB.x + laneoff));
    uint2 g5 = *(const uint2*)(hcb + (unsigned)(cB.y + laneoff));
    uint2 g6 = *(const uint2*)(hcb + (unsigned)(cB.z + laneoff));
    uint2 g7 = *(const uint2*)(hcb + (unsigned)(cB.w + laneoff));
    // oct 1 indices/alphas (clamped)
    int jn = (s0 + 8 < s1) ? s0 + 8 : s0;
    int4 cA2 = *(const int4*)(csr_b + jn);
    int4 cB2 = *(const int4*)(csr_b + jn + 4);
    float4 pA2 = *(const float4*)(aep + jn);
    float4 pB2 = *(const float4*)(aep + jn + 4);

    for (int j = s0 + 8; j < s1; j += 8) {
        uint2 m0 = *(const uint2*)(hcb + (unsigned)(cA2.x + laneoff));
        uint2 m1 = *(const uint2*)(hcb + (unsigned)(cA2.y + laneoff));
        uint2 m2 = *(const uint2*)(hcb + (unsigned)(cA2.z + laneoff));
        uint2 m3 = *(const uint2*)(hcb + (unsigned)(cA2.w + laneoff));
        uint2 m4 = *(const uint2*)(hcb + (unsigned)(cB2.x + laneoff));
        uint2 m5 = *(const uint2*)(hcb + (unsigned)(cB2.y + laneoff));
        uint2 m6 = *(const uint2*)(hcb + (unsigned)(cB2.z + laneoff));
        uint2 m7 = *(const uint2*)(hcb + (unsigned)(cB2.w + laneoff));
        int j2 = (j + 8 < s1) ? j + 8 : j;
        int4 cA3 = *(const int4*)(csr_b + j2);
        int4 cB3 = *(const int4*)(csr_b + j2 + 4);
        float4 pA3 = *(const float4*)(aep + j2);
        float4 pB3 = *(const float4*)(aep + j2 + 4);
        EDGE_FMA(pA.x, g0) EDGE_FMA(pA.y, g1) EDGE_FMA(pA.z, g2) EDGE_FMA(pA.w, g3)
        EDGE_FMA(pB.x, g4) EDGE_FMA(pB.y, g5) EDGE_FMA(pB.z, g6) EDGE_FMA(pB.w, g7)
        g0 = m0; g1 = m1; g2 = m2; g3 = m3; g4 = m4; g5 = m5; g6 = m6; g7 = m7;
        pA = pA2; pB = pB2;
        cA2 = cA3; cB2 = cB3; pA2 = pA3; pB2 = pB3;
    }
    EDGE_FMA(pA.x, g0) EDGE_FMA(pA.y, g1) EDGE_FMA(pA.z, g2) EDGE_FMA(pA.w, g3)
    EDGE_FMA(pB.x, g4) EDGE_FMA(pB.y, g5) EDGE_FMA(pB.z, g6) EDGE_FMA(pB.w, g7)

    // per-head normalize, then fold heads (lanes cl, cl+16, cl+32, cl+48 share channel)
    float inv = 1.f / (sacc + 1e-16f);
    float4 v = make_float4(acc.x * inv, acc.y * inv, acc.z * inv, acc.w * inv);
#pragma unroll
    for (int o = 16; o < 64; o <<= 1) {
        v.x += __shfl_xor(v.x, o);
        v.y += __shfl_xor(v.y, o);
        v.z += __shfl_xor(v.z, o);
        v.w += __shfl_xor(v.w, o);
    }
    if (lane < 16) {
        float4 b4 = *(const float4*)(bias + cl * 4);
        float ox = v.x * 0.25f + b4.x;
        float oy = v.y * 0.25f + b4.y;
        float oz = v.z * 0.25f + b4.z;
        float ow = v.w * 0.25f + b4.w;
        if (LAYER1) {
            ox = ox > 0.f ? ox : expm1f(ox);
            oy = oy > 0.f ? oy : expm1f(oy);
            oz = oz > 0.f ? oz : expm1f(oz);
            ow = ow > 0.f ? ow : expm1f(ow);
            __half2 lo = __floats2half2_rn(ox, oy);
            __half2 hi = __floats2half2_rn(oz, ow);
            uint2 pk = make_uint2(*(unsigned*)&lo, *(unsigned*)&hi);
            *(uint2*)((__half*)outv + ((size_t)b * N_NODES + dst) * 64 + cl * 4) = pk;
        } else {
            *(float4*)((float*)outv + ((size_t)b * N_NODES + dst) * 64 + cl * 4) =
                make_float4(ox, oy, oz, ow);
        }
    }
}

// ---------------- Launch: 9 dispatches, all compute-queue ----------------

extern "C" void kernel_launch(void* const* d_in, const int* in_sizes, int n_in,
                              void* d_out, int out_size, void* d_ws, size_t ws_size,
                              hipStream_t stream) {
    const float* x = (const float*)d_in[0];
    const int* ei = (const int*)d_in[1];
    const float* W1 = (const float*)d_in[2];
    const float* as1 = (const float*)d_in[3];
    const float* ad1 = (const float*)d_in[4];
    const float* b1 = (const float*)d_in[5];
    const float* W2 = (const float*)d_in[6];
    const float* as2 = (const float*)d_in[7];
    const float* ad2 = (const float*)d_in[8];
    const float* b2 = (const float*)d_in[9];
    float* out = (float*)d_out;

    // workspace layout (all segments 16B-aligned by construction)
    char* p = (char*)d_ws;
    int* deg = (int*)p;            p += sizeof(int) * N_PAD;
    int* offs = (int*)p;           p += sizeof(int) * (N_NODES + 4);
    int* cursor = (int*)p;         p += sizeof(int) * N_NODES;
    int* csr_b = (int*)p;          p += sizeof(int) * E_OCT;
    __half* Wt1 = (__half*)p;      p += sizeof(__half) * 272 * F_IN_C;
    __half* Wt2 = (__half*)p;      p += sizeof(__half) * 272 * HID_C;
    float* alsrc = (float*)p;      p += sizeof(float) * B_BATCH * SN * 4;
    float* aldst = (float*)p;      p += sizeof(float) * B_BATCH * SN * 4;
    __half* h2 = (__half*)p;       p += sizeof(__half) * (size_t)B_BATCH * SH * 256;
    __half* x2 = (__half*)p;       p += sizeof(__half) * (size_t)B_BATCH * N_NODES * 64;
    float* alse = (float*)p;       p += sizeof(float) * (size_t)B_BATCH * 4 * E_OCT;

    dim3 gAlse((E_OCT + 255) / 256, B_BATCH);

    // D0: deg = 0
    k_zero<<<N_PAD / 256, 256, 0, stream>>>(deg);
    // D1: wext1 | wext2 | csr sentinel fill | dummy rows | deg_count
    k_setup<<<1768, 256, 0, stream>>>(W1, as1, ad1, W2, as2, ad2, Wt1, Wt2,
                                      csr_b, h2, alsrc, deg, ei);
    // D2: scan (block 0) || gemm layer 1 (blocks 1..2500)
    k_gemm1_scan<<<2501, 256, 0, stream>>>(x, Wt1, h2, alsrc, aldst, deg, offs, cursor);
    // D3: scatter
    k_scatter<<<(E_TOT + 255) / 256, 256, 0, stream>>>(ei, cursor, csr_b);
    // D4: edge-ordered alpha-source (layer 1)
    k_alse<<<gAlse, 256, 0, stream>>>(csr_b, alsrc, alse);
    // D5: layer-1 aggregate -> x2 (fp16)
    k_agg<true><<<B_BATCH * 2500, 256, 0, stream>>>(h2, alse, aldst, offs, csr_b, b1, x2);
    // D6: gemm layer 2
    k_gemm2<<<dim3(625, B_BATCH), 256, 0, stream>>>(x2, Wt2, h2, alsrc, aldst);
    // D7: edge-ordered alpha-source (layer 2)
    k_alse<<<gAlse, 256, 0, stream>>>(csr_b, alsrc, alse);
    // D8: layer-2 aggregate -> out (f32)
    k_agg<false><<<B_BATCH * 2500, 256, 0, stream>>>(h2, alse, aldst, offs, csr_b, b2, out);
}

// Round 23
// 179.298 us; speedup vs baseline: 1.0686x; 1.0686x over previous
//
#include <hip/hip_runtime.h>
#include <hip/hip_fp16.h>
#include <math.h>

#define N_NODES 10000
#define N_PAD 10240    // deg array padded for int4 scan reads
#define B_BATCH 4
#define F_IN_C 128
#define HID_C 64
#define E_EDGES 160000
#define E_TOT (E_EDGES + N_NODES)
#define E_OCT 240000   // E_TOT + 7*N_NODES upper bound (oct-padded)
#define NEG_SLOPE 0.2f
#define LOG2E 1.44269504f
#define SN (N_NODES + 8)   // alsrc/aldst node stride per batch (row N = dummy, -1e30)
#define SH (N_NODES + 8)   // h2 rows per batch (row N = dummy, zeros)

typedef _Float16 half8 __attribute__((ext_vector_type(8)));
typedef float f32x4 __attribute__((ext_vector_type(4)));

// ---------------- deg zero ----------------

__global__ void k_zero(int* __restrict__ deg) {
    deg[blockIdx.x * 256 + threadIdx.x] = 0;   // 40 blocks x 256 == N_PAD exactly
}

// ---------------- Wt_ext: fp16 col-major [272][K]; 256+hd=W@a_src, 260+hd=W@a_dst --------------
// al columns pre-scaled by log2(e) (leaky is positively homogeneous -> raw v_exp_f32 in k_agg).

__device__ void wext_body(const float* __restrict__ W, const float* __restrict__ asrc,
                          const float* __restrict__ adst, __half* __restrict__ Wt,
                          int tid, int K) {
    int nc = tid / K, k = tid % K;
    float v;
    if (nc < 256) {
        v = W[k * 256 + nc];
    } else if (nc < 260) {
        int hd = nc - 256; v = 0.f;
        for (int c = 0; c < 64; c++) v += W[k * 256 + hd * 64 + c] * asrc[hd * 64 + c];
        v *= LOG2E;
    } else if (nc < 264) {
        int hd = nc - 260; v = 0.f;
        for (int c = 0; c < 64; c++) v += W[k * 256 + hd * 64 + c] * adst[hd * 64 + c];
        v *= LOG2E;
    } else {
        v = 0.f;
    }
    Wt[(size_t)nc * K + k] = __float2half(v);
}

// ---------------- Mega-setup: wext1 | wext2 | csr sentinel-fill | dummy rows | deg_count --------

__global__ void k_setup(const float* __restrict__ W1, const float* __restrict__ as1,
                        const float* __restrict__ ad1, const float* __restrict__ W2,
                        const float* __restrict__ as2, const float* __restrict__ ad2,
                        __half* __restrict__ Wt1, __half* __restrict__ Wt2,
                        int* __restrict__ csr_b, __half* __restrict__ h2,
                        float* __restrict__ alsrc, int* __restrict__ deg,
                        const int* __restrict__ ei) {
    int blk = blockIdx.x, t = threadIdx.x;
    if (blk < 136) {
        wext_body(W1, as1, ad1, Wt1, blk * 256 + t, F_IN_C);
    } else if (blk < 204) {
        wext_body(W2, as2, ad2, Wt2, (blk - 136) * 256 + t, HID_C);
    } else if (blk < 1142) {
        int i = (blk - 204) * 256 + t;
        if (i < E_OCT) csr_b[i] = N_NODES << 9;   // dummy sentinel
    } else if (blk == 1142) {
        for (int i = t; i < 4 * 256; i += 256) {   // dummy h2 rows = 0
            int b = i >> 8, c = i & 255;
            h2[((size_t)b * SH + N_NODES) * 256 + c] = __float2half(0.f);
        }
        if (t < 16) {                              // dummy alsrc = -1e30
            int b = t >> 2, q = t & 3;
            alsrc[((size_t)b * SN + N_NODES) * 4 + q] = -1e30f;
        }
    } else {
        int e = (blk - 1143) * 256 + t;
        if (e < E_EDGES) atomicAdd(&deg[ei[E_EDGES + e]], 1);
    }
}

// ---------------- MFMA GEMM body: h = x@W (fp16 in, f32 accum, node-major fp16 out) ------------

template <int K, typename XT>
__device__ void gemm_body(const XT* __restrict__ x, const __half* __restrict__ Wt,
                          __half* __restrict__ h2, float* __restrict__ alsrc,
                          float* __restrict__ aldst, int b, int tile) {
    int t = threadIdx.x;
    int w = t >> 6, lane = t & 63;
    int node0 = tile * 16;
    int col = lane & 15, kblk = lane >> 4;

    const XT* xr = x + ((size_t)b * N_NODES + node0 + col) * K + kblk * 8;

    f32x4 acc0 = {0.f, 0.f, 0.f, 0.f};
    f32x4 acc1 = {0.f, 0.f, 0.f, 0.f};
    f32x4 acc2 = {0.f, 0.f, 0.f, 0.f};
    f32x4 acc3 = {0.f, 0.f, 0.f, 0.f};
    f32x4 accal = {0.f, 0.f, 0.f, 0.f};

#pragma unroll
    for (int k0 = 0; k0 < K; k0 += 32) {
        half8 a;
        if constexpr (sizeof(XT) == 4) {
            float4 xa = *(const float4*)(xr + k0);
            float4 xc = *(const float4*)(xr + k0 + 4);
            a[0] = (_Float16)xa.x; a[1] = (_Float16)xa.y; a[2] = (_Float16)xa.z; a[3] = (_Float16)xa.w;
            a[4] = (_Float16)xc.x; a[5] = (_Float16)xc.y; a[6] = (_Float16)xc.z; a[7] = (_Float16)xc.w;
        } else {
            a = *(const half8*)(xr + k0);
        }
        const __half* wtk = Wt + kblk * 8 + k0;
        half8 b0 = *(const half8*)(wtk + (size_t)((w * 4 + 0) * 16 + col) * K);
        half8 b1 = *(const half8*)(wtk + (size_t)((w * 4 + 1) * 16 + col) * K);
        half8 b2 = *(const half8*)(wtk + (size_t)((w * 4 + 2) * 16 + col) * K);
        half8 b3 = *(const half8*)(wtk + (size_t)((w * 4 + 3) * 16 + col) * K);
        acc0 = __builtin_amdgcn_mfma_f32_16x16x32_f16(a, b0, acc0, 0, 0, 0);
        acc1 = __builtin_amdgcn_mfma_f32_16x16x32_f16(a, b1, acc1, 0, 0, 0);
        acc2 = __builtin_amdgcn_mfma_f32_16x16x32_f16(a, b2, acc2, 0, 0, 0);
        acc3 = __builtin_amdgcn_mfma_f32_16x16x32_f16(a, b3, acc3, 0, 0, 0);
        if (w == 0) {
            half8 bal = *(const half8*)(wtk + (size_t)(256 + col) * K);
            accal = __builtin_amdgcn_mfma_f32_16x16x32_f16(a, bal, accal, 0, 0, 0);
        }
    }

    {   // node-major store: h2[(b*SH + node)*256 + w*64 + nt*16 + col]
        __half* dst = h2 + ((size_t)b * SH + node0 + kblk * 4) * 256 + w * 64 + col;
#pragma unroll
        for (int r = 0; r < 4; r++) dst[(size_t)r * 256 + 0 * 16] = __float2half(acc0[r]);
#pragma unroll
        for (int r = 0; r < 4; r++) dst[(size_t)r * 256 + 1 * 16] = __float2half(acc1[r]);
#pragma unroll
        for (int r = 0; r < 4; r++) dst[(size_t)r * 256 + 2 * 16] = __float2half(acc2[r]);
#pragma unroll
        for (int r = 0; r < 4; r++) dst[(size_t)r * 256 + 3 * 16] = __float2half(acc3[r]);
    }
    if (w == 0 && col < 8) {
        int node = node0 + kblk * 4;
        if (col < 4) {
            float* d = alsrc + ((size_t)b * SN + node) * 4 + col;
#pragma unroll
            for (int r = 0; r < 4; r++) d[r * 4] = accal[r];
        } else {
            float* d = aldst + ((size_t)b * SN + node) * 4 + (col - 4);
#pragma unroll
            for (int r = 0; r < 4; r++) d[r * 4] = accal[r];
        }
    }
}

// ---------------- Scan (256 threads; int4-vectorized loads, fully pipelined) ----------------

__device__ void scan_body(const int* __restrict__ deg, int* __restrict__ offs,
                          int* __restrict__ cursor) {
    __shared__ int lds[256];
    int t = threadIdx.x;
    int i0 = t * 40;
    int v[40];
#pragma unroll
    for (int q = 0; q < 10; q++) {
        int4 d4 = *(const int4*)(deg + i0 + q * 4);
        v[q * 4 + 0] = (d4.x + 8) & ~7;   // (deg + 1 self-loop + 7) & ~7
        v[q * 4 + 1] = (d4.y + 8) & ~7;
        v[q * 4 + 2] = (d4.z + 8) & ~7;
        v[q * 4 + 3] = (d4.w + 8) & ~7;
    }
    int tot = 0;
#pragma unroll
    for (int j = 0; j < 40; j++) tot += v[j];
    lds[t] = tot;
    __syncthreads();
    for (int ofs = 1; ofs < 256; ofs <<= 1) {
        int w = (t >= ofs) ? lds[t - ofs] : 0;
        __syncthreads();
        lds[t] += w;
        __syncthreads();
    }
    int run = lds[t] - tot;
#pragma unroll
    for (int j = 0; j < 40; j++) {
        int i = i0 + j;
        if (i < N_NODES) {
            cursor[i] = run;
            offs[i + 1] = run + v[j];
        }
        run += v[j];
    }
    if (t == 0) offs[0] = 0;
}

// ---------------- Fused dispatch: scan (block 0) || gemm1 (blocks 1..2500) ----------------

__launch_bounds__(256)
__global__ void k_gemm1_scan(const float* __restrict__ x, const __half* __restrict__ Wt,
                             __half* __restrict__ h2, float* __restrict__ alsrc,
                             float* __restrict__ aldst, const int* __restrict__ deg,
                             int* __restrict__ offs, int* __restrict__ cursor) {
    int bid = blockIdx.x;
    if (bid == 0) { scan_body(deg, offs, cursor); return; }
    gemm_body<F_IN_C, float>(x, Wt, h2, alsrc, aldst, (bid - 1) / 625, (bid - 1) % 625);
}

__launch_bounds__(256)
__global__ void k_gemm2(const __half* __restrict__ x2, const __half* __restrict__ Wt,
                        __half* __restrict__ h2, float* __restrict__ alsrc,
                        float* __restrict__ aldst) {
    gemm_body<HID_C, __half>(x2, Wt, h2, alsrc, aldst, blockIdx.y, blockIdx.x);
}

// ---------------- Scatter: real edges overwrite sentinel fill ----------------

__global__ void k_scatter(const int* __restrict__ ei, int* __restrict__ cursor,
                          int* __restrict__ csr_b) {
    int e = blockIdx.x * 256 + threadIdx.x;
    if (e < E_TOT) {
        int s, d;
        if (e < E_EDGES) { s = ei[e]; d = ei[E_EDGES + e]; }
        else { s = d = e - E_EDGES; }
        int pos = atomicAdd(&cursor[d], 1);
        csr_b[pos] = s << 9;     // src * 512 bytes (node-major fp16 row)
    }
}

// ---------------- 4-head fused gather-aggregate, in-loop alpha, oct depth-2 pipeline ----------
// v_fma_mix_f32 consumes gathered fp16 directly; al pre-scaled by log2e -> raw v_exp_f32.
// Asm is register-only, deps fully in constraints. This structure is the measured floor:
// width-ILP (r11), depth pipelining (r15), fp16 lines (r12), coalescing (r17), VALU cuts
// (r20), VMEM-count cuts (r22) all null -- the random 512B row-gather rate binds.

#define EDGE_FMA(av, g)                                                                   \
    {                                                                                     \
        float v_ = av + ad_h;                                                             \
        v_ = fmaxf(v_, NEG_SLOPE * v_);                                                   \
        float e_;                                                                         \
        asm("v_exp_f32 %0, %1" : "=v"(e_) : "v"(v_));                                     \
        asm("v_fma_mix_f32 %0, %1, %2, %0 op_sel:[0,0,0] op_sel_hi:[1,0,0]"               \
            : "+v"(acc.x) : "v"(g.x), "v"(e_));                                           \
        asm("v_fma_mix_f32 %0, %1, %2, %0 op_sel:[1,0,0] op_sel_hi:[1,0,0]"               \
            : "+v"(acc.y) : "v"(g.x), "v"(e_));                                           \
        asm("v_fma_mix_f32 %0, %1, %2, %0 op_sel:[0,0,0] op_sel_hi:[1,0,0]"               \
            : "+v"(acc.z) : "v"(g.y), "v"(e_));                                           \
        asm("v_fma_mix_f32 %0, %1, %2, %0 op_sel:[1,0,0] op_sel_hi:[1,0,0]"               \
            : "+v"(acc.w) : "v"(g.y), "v"(e_));                                           \
        sacc += e_;                                                                       \
    }

template <bool LAYER1>
__launch_bounds__(256)
__global__ void k_agg(const __half* __restrict__ h2, const float* __restrict__ alsrc,
                      const float* __restrict__ aldst, const int* __restrict__ offs,
                      const int* __restrict__ csr_b, const float* __restrict__ bias,
                      void* __restrict__ outv) {
    int t = threadIdx.x;
    int bid = blockIdx.x;
    int xcd = bid & 7;
    int b = xcd >> 1;
    int local = (bid >> 3) * 2 + (xcd & 1); // 0..2499
    int wv = t >> 6, lane = t & 63;
    int hd = lane >> 4, cl = lane & 15;
    int dst = local * 4 + wv;

    const char* hcb = (const char*)(h2 + (size_t)b * SH * 256);
    const float* als = alsrc + (size_t)b * SN * 4 + hd;   // +hd folded into base
    float ad_h = aldst[((size_t)b * SN + dst) * 4 + hd];
    int s0 = offs[dst], s1 = offs[dst + 1];
    int laneoff = (hd << 7) | (cl << 3);    // head slice (128 B) + chan quad (8 B)

    float4 acc = make_float4(0.f, 0.f, 0.f, 0.f);
    float sacc = 0.f;
    // prologue: oct 0 fully staged (padded len >= 8)
    int4 cA = *(const int4*)(csr_b + s0);
    int4 cB = *(const int4*)(csr_b + s0 + 4);
    uint2 g0 = *(const uint2*)(hcb + (unsigned)(cA.x + laneoff));
    uint2 g1 = *(const uint2*)(hcb + (unsigned)(cA.y + laneoff));
    uint2 g2 = *(const uint2*)(hcb + (unsigned)(cA.z + laneoff));
    uint2 g3 = *(const uint2*)(hcb + (unsigned)(cA.w + laneoff));
    uint2 g4 = *(const uint2*)(hcb + (unsigned)(cB.x + laneoff));
    uint2 g5 = *(const uint2*)(hcb + (unsigned)(cB.y + laneoff));
    uint2 g6 = *(const uint2*)(hcb + (unsigned)(cB.z + laneoff));
    uint2 g7 = *(const uint2*)(hcb + (unsigned)(cB.w + laneoff));
    float a0 = als[cA.x >> 7], a1 = als[cA.y >> 7], a2 = als[cA.z >> 7], a3 = als[cA.w >> 7];
    float a4 = als[cB.x >> 7], a5 = als[cB.y >> 7], a6 = als[cB.z >> 7], a7 = als[cB.w >> 7];
    // oct 1 indices (clamped)
    int jn = (s0 + 8 < s1) ? s0 + 8 : s0;
    int4 cA2 = *(const int4*)(csr_b + jn);
    int4 cB2 = *(const int4*)(csr_b + jn + 4);

    for (int j = s0 + 8; j < s1; j += 8) {
        uint2 m0 = *(const uint2*)(hcb + (unsigned)(cA2.x + laneoff));
        uint2 m1 = *(const uint2*)(hcb + (unsigned)(cA2.y + laneoff));
        uint2 m2 = *(const uint2*)(hcb + (unsigned)(cA2.z + laneoff));
        uint2 m3 = *(const uint2*)(hcb + (unsigned)(cA2.w + laneoff));
        uint2 m4 = *(const uint2*)(hcb + (unsigned)(cB2.x + laneoff));
        uint2 m5 = *(const uint2*)(hcb + (unsigned)(cB2.y + laneoff));
        uint2 m6 = *(const uint2*)(hcb + (unsigned)(cB2.z + laneoff));
        uint2 m7 = *(const uint2*)(hcb + (unsigned)(cB2.w + laneoff));
        float v0 = als[cA2.x >> 7], v1 = als[cA2.y >> 7], v2 = als[cA2.z >> 7], v3 = als[cA2.w >> 7];
        float v4 = als[cB2.x >> 7], v5 = als[cB2.y >> 7], v6 = als[cB2.z >> 7], v7 = als[cB2.w >> 7];
        int j2 = (j + 8 < s1) ? j + 8 : j;
        int4 cA3 = *(const int4*)(csr_b + j2);
        int4 cB3 = *(const int4*)(csr_b + j2 + 4);
        EDGE_FMA(a0, g0) EDGE_FMA(a1, g1) EDGE_FMA(a2, g2) EDGE_FMA(a3, g3)
        EDGE_FMA(a4, g4) EDGE_FMA(a5, g5) EDGE_FMA(a6, g6) EDGE_FMA(a7, g7)
        g0 = m0; g1 = m1; g2 = m2; g3 = m3; g4 = m4; g5 = m5; g6 = m6; g7 = m7;
        a0 = v0; a1 = v1; a2 = v2; a3 = v3; a4 = v4; a5 = v5; a6 = v6; a7 = v7;
        cA2 = cA3; cB2 = cB3;
    }
    EDGE_FMA(a0, g0) EDGE_FMA(a1, g1) EDGE_FMA(a2, g2) EDGE_FMA(a3, g3)
    EDGE_FMA(a4, g4) EDGE_FMA(a5, g5) EDGE_FMA(a6, g6) EDGE_FMA(a7, g7)

    // per-head normalize, then fold heads (lanes cl, cl+16, cl+32, cl+48 share channel)
    float inv = 1.f / (sacc + 1e-16f);
    float4 v = make_float4(acc.x * inv, acc.y * inv, acc.z * inv, acc.w * inv);
#pragma unroll
    for (int o = 16; o < 64; o <<= 1) {
        v.x += __shfl_xor(v.x, o);
        v.y += __shfl_xor(v.y, o);
        v.z += __shfl_xor(v.z, o);
        v.w += __shfl_xor(v.w, o);
    }
    if (lane < 16) {
        float4 b4 = *(const float4*)(bias + cl * 4);
        float ox = v.x * 0.25f + b4.x;
        float oy = v.y * 0.25f + b4.y;
        float oz = v.z * 0.25f + b4.z;
        float ow = v.w * 0.25f + b4.w;
        if (LAYER1) {
            ox = ox > 0.f ? ox : expm1f(ox);
            oy = oy > 0.f ? oy : expm1f(oy);
            oz = oz > 0.f ? oz : expm1f(oz);
            ow = ow > 0.f ? ow : expm1f(ow);
            __half2 lo = __floats2half2_rn(ox, oy);
            __half2 hi = __floats2half2_rn(oz, ow);
            uint2 pk = make_uint2(*(unsigned*)&lo, *(unsigned*)&hi);
            *(uint2*)((__half*)outv + ((size_t)b * N_NODES + dst) * 64 + cl * 4) = pk;
        } else {
            *(float4*)((float*)outv + ((size_t)b * N_NODES + dst) * 64 + cl * 4) =
                make_float4(ox, oy, oz, ow);
        }
    }
}

// ---------------- Launch: 7 dispatches, all compute-queue ----------------

extern "C" void kernel_launch(void* const* d_in, const int* in_sizes, int n_in,
                              void* d_out, int out_size, void* d_ws, size_t ws_size,
                              hipStream_t stream) {
    const float* x = (const float*)d_in[0];
    const int* ei = (const int*)d_in[1];
    const float* W1 = (const float*)d_in[2];
    const float* as1 = (const float*)d_in[3];
    const float* ad1 = (const float*)d_in[4];
    const float* b1 = (const float*)d_in[5];
    const float* W2 = (const float*)d_in[6];
    const float* as2 = (const float*)d_in[7];
    const float* ad2 = (const float*)d_in[8];
    const float* b2 = (const float*)d_in[9];
    float* out = (float*)d_out;

    // workspace layout (all segments 16B-aligned by construction)
    char* p = (char*)d_ws;
    int* deg = (int*)p;            p += sizeof(int) * N_PAD;
    int* offs = (int*)p;           p += sizeof(int) * (N_NODES + 4);
    int* cursor = (int*)p;         p += sizeof(int) * N_NODES;
    int* csr_b = (int*)p;          p += sizeof(int) * E_OCT;
    __half* Wt1 = (__half*)p;      p += sizeof(__half) * 272 * F_IN_C;
    __half* Wt2 = (__half*)p;      p += sizeof(__half) * 272 * HID_C;
    float* alsrc = (float*)p;      p += sizeof(float) * B_BATCH * SN * 4;
    float* aldst = (float*)p;      p += sizeof(float) * B_BATCH * SN * 4;
    __half* h2 = (__half*)p;       p += sizeof(__half) * (size_t)B_BATCH * SH * 256;
    __half* x2 = (__half*)p;       p += sizeof(__half) * (size_t)B_BATCH * N_NODES * 64;

    // D0: deg = 0 (kernel, not memset -- keeps everything on the compute queue)
    k_zero<<<N_PAD / 256, 256, 0, stream>>>(deg);
    // D1: wext1 | wext2 | csr sentinel fill | dummy rows | deg_count
    k_setup<<<1768, 256, 0, stream>>>(W1, as1, ad1, W2, as2, ad2, Wt1, Wt2,
                                      csr_b, h2, alsrc, deg, ei);
    // D2: scan (block 0, int4-vectorized) || gemm layer 1 (blocks 1..2500)
    k_gemm1_scan<<<2501, 256, 0, stream>>>(x, Wt1, h2, alsrc, aldst, deg, offs, cursor);
    // D3: scatter (overwrites sentinel fill with real edges)
    k_scatter<<<(E_TOT + 255) / 256, 256, 0, stream>>>(ei, cursor, csr_b);
    // D4: layer-1 aggregate (alpha in-loop) -> x2 (fp16)
    k_agg<true><<<B_BATCH * 2500, 256, 0, stream>>>(h2, alsrc, aldst, offs, csr_b, b1, x2);
    // D5: gemm layer 2
    k_gemm2<<<dim3(625, B_BATCH), 256, 0, stream>>>(x2, Wt2, h2, alsrc, aldst);
    // D6: layer-2 aggregate -> out (f32)
    k_agg<false><<<B_BATCH * 2500, 256, 0, stream>>>(h2, alsrc, aldst, offs, csr_b, b2, out);
}